// Round 1
// baseline (5175.058 us; speedup 1.0000x reference)
//
#include <hip/hip_runtime.h>
#include <hip/hip_bf16.h>
#include <math.h>

// Problem constants
#define NQ 8
#define DIMV 256
#define KCODES 1024
#define NTOK 65536              // 32*2048
#define NELEM (NTOK * DIMV)     // 16777216

// ---------------------------------------------------------------------------
// Pre-pass: transpose embeds [q][d][k] -> embedT [q][k][d]
// ---------------------------------------------------------------------------
__global__ __launch_bounds__(256)
void vq_transpose(const float* __restrict__ embeds, float* __restrict__ embedT) {
    const int idx = blockIdx.x * 256 + threadIdx.x;       // 0 .. 2097151
    const int q   = idx >> 18;
    const int rem = idx & 262143;
    const int k   = rem >> 8;
    const int d   = rem & 255;
    embedT[idx] = embeds[q * 262144 + d * 1024 + k];
}

// e2[q][k] = sum_d embed[q][d][k]^2
__global__ __launch_bounds__(256)
void vq_e2(const float* __restrict__ embeds, float* __restrict__ e2) {
    const int idx = blockIdx.x * 256 + threadIdx.x;       // 0 .. 8191
    const int q = idx >> 10;
    const int k = idx & 1023;
    const float* e = embeds + q * 262144 + k;
    float s = 0.f;
    for (int d = 0; d < DIMV; ++d) {
        const float v = e[d * 1024];
        s += v * v;
    }
    e2[idx] = s;
}

// ---------------------------------------------------------------------------
// Kernel A: per-token argmin over 1024 codes.
// Block = 512 threads (8 waves), 64 tokens/block.
// Wave w handles code range [w*128, (w+1)*128) in 2 chunks of 64.
// x tile staged in LDS with add-rotate swizzle (conflict-free both ways).
// ---------------------------------------------------------------------------
__global__ __launch_bounds__(512)
void vq_argmin(const float* __restrict__ resIn, const float* __restrict__ embed,
               const float* __restrict__ e2, int* __restrict__ ind,
               int* __restrict__ counts) {
    __shared__ float xT[64 * 256];   // 64 KB; reused for the argmin reduction
    const int tid = threadIdx.x;
    const int blockTok = blockIdx.x * 64;

    // Stage 64 tokens x 256 dims, swizzled: element (t,d) at xT[t*256 + ((d+t)&255)]
    {
        const int d = tid & 255;
        const int half = tid >> 8;            // 0 or 1
        for (int i = 0; i < 32; ++i) {
            const int t = i * 2 + half;
            xT[t * 256 + ((d + t) & 255)] = resIn[(blockTok + t) * 256 + d];
        }
    }
    __syncthreads();

    const int t = tid & 63;      // token lane
    const int w = tid >> 6;      // wave id 0..7  -> code range base w*128

    float best = 3.4e38f;
    int bi = 0;
    const float* xrow = xT + t * 256;

    for (int c = 0; c < 2; ++c) {
        const int k0 = __builtin_amdgcn_readfirstlane(w * 128 + c * 64);
        float acc[64];
#pragma unroll
        for (int j = 0; j < 64; ++j) acc[j] = 0.f;
        for (int d = 0; d < DIMV; ++d) {
            const float xv = xrow[(d + t) & 255];
            const float* e = embed + d * 1024 + k0;   // wave-uniform address
#pragma unroll
            for (int j = 0; j < 64; ++j) acc[j] = fmaf(xv, e[j], acc[j]);
        }
#pragma unroll
        for (int j = 0; j < 64; ++j) {
            const float s = e2[k0 + j] - 2.0f * acc[j];
            if (s < best) { best = s; bi = k0 + j; }   // strict < keeps first min
        }
    }
    __syncthreads();   // xT no longer needed; reuse as reduction scratch

    float* bestD_s = xT;                   // [8][64]
    int*   bestI_s = (int*)(xT + 512);     // [8][64]
    bestD_s[w * 64 + t] = best;
    bestI_s[w * 64 + t] = bi;
    __syncthreads();

    if (tid < 64) {
        float b = bestD_s[tid];
        int idx = bestI_s[tid];
        for (int w2 = 1; w2 < 8; ++w2) {          // ascending code ranges: tie -> first
            const float bw = bestD_s[w2 * 64 + tid];
            if (bw < b) { b = bw; idx = bestI_s[w2 * 64 + tid]; }
        }
        ind[blockTok + tid] = idx;
        atomicAdd(&counts[idx], 1);
    }
}

// ---------------------------------------------------------------------------
// Kernel B: quantize gather + residual/out update + commitment-loss reduce.
// One thread = one float4; one wave = exactly one token row (64*4 = 256 dims).
// ---------------------------------------------------------------------------
__global__ __launch_bounds__(256)
void vq_update(const float* __restrict__ resIn, const float* __restrict__ embedT,
               const int* __restrict__ ind, float* __restrict__ resOut,
               float* __restrict__ out, float* __restrict__ lossSum,
               const int first) {
    const int i = blockIdx.x * 256 + threadIdx.x;    // float4 index, 0..4194303
    const int n = i >> 6;                            // token
    const int d4 = (i & 63) << 2;                    // dim offset
    const int bi = ind[n];                           // wave-uniform

    const float4 q4 = *(const float4*)(embedT + bi * 256 + d4);
    const float4 r4 = *(const float4*)(resIn + i * 4);

    float4 nr;
    nr.x = r4.x - q4.x; nr.y = r4.y - q4.y;
    nr.z = r4.z - q4.z; nr.w = r4.w - q4.w;
    *(float4*)(resOut + i * 4) = nr;

    float4 o4;
    if (first) {
        o4 = q4;
    } else {
        o4 = *(const float4*)(out + i * 4);
        o4.x += q4.x; o4.y += q4.y; o4.z += q4.z; o4.w += q4.w;
    }
    *(float4*)(out + i * 4) = o4;

    // (q - r)^2 == (r - q)^2 == nr^2
    float l = nr.x * nr.x + nr.y * nr.y + nr.z * nr.z + nr.w * nr.w;
    for (int off = 32; off > 0; off >>= 1) l += __shfl_down(l, off);
    __shared__ float wpart[4];
    if ((threadIdx.x & 63) == 0) wpart[threadIdx.x >> 6] = l;
    __syncthreads();
    if (threadIdx.x == 0)
        atomicAdd(lossSum, wpart[0] + wpart[1] + wpart[2] + wpart[3]);
}

// ---------------------------------------------------------------------------
// Finalize: losses + perplexities into the output tail.
// ---------------------------------------------------------------------------
__global__ __launch_bounds__(256)
void vq_finalize(const int* __restrict__ counts, const float* __restrict__ lossSum,
                 float* __restrict__ outTail) {
    const int q = blockIdx.x;
    const int tid = threadIdx.x;
    float s = 0.f;
    for (int k = tid; k < KCODES; k += 256) {
        const float p = (float)counts[q * KCODES + k] * (1.0f / 65536.0f);
        s += p * logf(p + 1e-10f);
    }
    for (int off = 32; off > 0; off >>= 1) s += __shfl_down(s, off);
    __shared__ float wpart[4];
    if ((tid & 63) == 0) wpart[tid >> 6] = s;
    __syncthreads();
    if (tid == 0) {
        outTail[q]     = lossSum[q] * (1.0f / 16777216.0f);   // mean * COMMITMENT(=1)
        outTail[8 + q] = expf(-(wpart[0] + wpart[1] + wpart[2] + wpart[3]));
    }
}

// ---------------------------------------------------------------------------
extern "C" void kernel_launch(void* const* d_in, const int* in_sizes, int n_in,
                              void* d_out, int out_size, void* d_ws, size_t ws_size,
                              hipStream_t stream) {
    const float* x      = (const float*)d_in[0];   // [32,2048,256]
    const float* embeds = (const float*)d_in[1];   // [8,256,1024]
    float* out = (float*)d_out;                    // 16777216 + 8 + 8

    // Workspace layout (floats):
    float* residual = (float*)d_ws;                 // 16777216
    float* embedT   = residual + NELEM;             // 2097152
    float* e2       = embedT + NQ * KCODES * DIMV;  // 8192
    float* lossSum  = e2 + NQ * KCODES;             // 8
    int*   counts   = (int*)(lossSum + NQ);         // 8192
    int*   ind      = counts + NQ * KCODES;         // 65536
    // total ~75.9 MB

    // zero lossSum + counts (contiguous)
    hipMemsetAsync(lossSum, 0, (NQ + NQ * KCODES) * sizeof(float), stream);

    vq_transpose<<<8192, 256, 0, stream>>>(embeds, embedT);
    vq_e2<<<32, 256, 0, stream>>>(embeds, e2);

    for (int q = 0; q < NQ; ++q) {
        const float* resIn = (q == 0) ? x : residual;
        vq_argmin<<<NTOK / 64, 512, 0, stream>>>(
            resIn, embeds + q * (DIMV * KCODES), e2 + q * KCODES,
            ind, counts + q * KCODES);
        vq_update<<<NELEM / 4 / 256, 256, 0, stream>>>(
            resIn, embedT + q * (KCODES * DIMV), ind, residual,
            out, lossSum + q, q == 0 ? 1 : 0);
    }
    vq_finalize<<<NQ, 256, 0, stream>>>(counts, lossSum, out + NELEM);
}

// Round 2
// 2099.173 us; speedup vs baseline: 2.4653x; 2.4653x over previous
//
#include <hip/hip_runtime.h>
#include <hip/hip_bf16.h>
#include <math.h>
#include <stdint.h>

// Problem constants
#define NQ 8
#define DIMV 256
#define KCODES 1024
#define NTOK 65536              // 32*2048
#define NELEM (NTOK * DIMV)     // 16777216
#define TOKPB 64                // tokens per block in fused kernel

typedef _Float16 f16x8 __attribute__((ext_vector_type(8)));
typedef float    f32x16 __attribute__((ext_vector_type(16)));

#define AS3 __attribute__((address_space(3)))
#define AS1 __attribute__((address_space(1)))

// ---------------------------------------------------------------------------
// Pre-pass 1: transpose embeds [q][d][k] -> embedT [q][k][d] (fp32, for the
// quantize gather in the update phase).
// ---------------------------------------------------------------------------
__global__ __launch_bounds__(256)
void vq_transpose(const float* __restrict__ embeds, float* __restrict__ embedT) {
    const int idx = blockIdx.x * 256 + threadIdx.x;       // 0 .. 2097151
    const int q   = idx >> 18;
    const int rem = idx & 262143;
    const int k   = rem >> 8;
    const int d   = rem & 255;
    embedT[idx] = embeds[q * 262144 + d * 1024 + k];
}

// Pre-pass 2: e2[q][k] = sum_d embed[q][d][k]^2 (fp32)
__global__ __launch_bounds__(256)
void vq_e2(const float* __restrict__ embeds, float* __restrict__ e2) {
    const int idx = blockIdx.x * 256 + threadIdx.x;       // 0 .. 8191
    const int q = idx >> 10;
    const int k = idx & 1023;
    const float* e = embeds + q * 262144 + k;
    float s = 0.f;
    for (int d = 0; d < DIMV; ++d) {
        const float v = e[d * 1024];
        s += v * v;
    }
    e2[idx] = s;
}

// ---------------------------------------------------------------------------
// Pre-pass 3: split embed into fp16 hi/lo and lay it out as the EXACT LDS
// image the fused kernel stages per 16-dim chunk:
//   embedB[q][chunk(16)][part(hi=0,lo=1)][slot(2048)][j(8 halfs)]
// slot s <-> (code c, k-half h): g=s>>3, t=(s&7)^(g&7), c=g*4+(t>>1), h=t&1.
// (forward: slot = (c>>2)*8 + ((2*c+h)&7 ^ ((c>>2)&7)) — XOR bank swizzle)
// d = chunk*16 + h*8 + j.
// ---------------------------------------------------------------------------
__global__ __launch_bounds__(256)
void vq_embedB(const float* __restrict__ embeds, _Float16* __restrict__ embedB) {
    const int idx = blockIdx.x * 256 + threadIdx.x;       // 0 .. 2097151
    const int j     = idx & 7;
    const int s     = (idx >> 3) & 2047;
    const int chunk = (idx >> 14) & 15;
    const int q     = idx >> 18;
    const int g   = s >> 3;
    const int t   = (s & 7) ^ (g & 7);
    const int c   = g * 4 + (t >> 1);
    const int h   = t & 1;
    const int d   = chunk * 16 + h * 8 + j;
    const float v = embeds[q * 262144 + d * 1024 + c];
    const _Float16 hi = (_Float16)v;
    const _Float16 lo = (_Float16)(v - (float)hi);
    const int base = (q * 16 + chunk) * 32768 + s * 8 + j;  // halfs
    embedB[base]         = hi;
    embedB[base + 16384] = lo;
}

// ---------------------------------------------------------------------------
// Fused residual-VQ kernel: 1024 blocks x 512 threads, 64 tokens/block.
// Residual kept in LDS as fp16 hi/lo across all 8 layers.
// Distances via 3-pass fp16 MFMA (hi*Hi + hi*Lo + lo*Hi), fp32 accumulate.
// ---------------------------------------------------------------------------
// LDS layout (bytes):
//  [0,       32768)  A_hi : 64 rows x 256 d fp16, row = t*512B, slot s(=d>>3)
//                            stored at (s ^ (t&31))*16   (XOR swizzle)
//  [32768,   65536)  A_lo : same layout
//  [65536,  131072)  B chunk image: [part][2048 slots][16B]  (hi at 65536,
//                            lo at 65536+32768) == embedB[q][chunk] verbatim
//  [131072, 133120)  bestS  float[8][64]
//  [133120, 135168)  bestI  int  [8][64]
//  [135168, 135424)  indF   int  [64]
//  [135424, 135456)  lossRed float[8]
#define LDS_BYTES 135456

__global__ __launch_bounds__(512, 2)
void vq_fused(const float* __restrict__ x, const float* __restrict__ embedT,
              const float* __restrict__ e2g, const _Float16* __restrict__ embedB,
              float* __restrict__ out, float* __restrict__ lossSum,
              int* __restrict__ counts) {
    extern __shared__ char smem[];
    _Float16* Ahi = (_Float16*)smem;
    _Float16* Alo = (_Float16*)(smem + 32768);
    float* bestS   = (float*)(smem + 131072);
    int*   bestI   = (int*)(smem + 133120);
    int*   indF    = (int*)(smem + 135168);
    float* lossRed = (float*)(smem + 135424);

    const int tid    = threadIdx.x;
    const int wave   = tid >> 6;
    const int lane   = tid & 63;
    const int l32    = lane & 31;
    const int h32    = lane >> 5;
    const int tok0   = blockIdx.x * TOKPB;
    const int codeBase = wave * 128;

    // ---- Phase 0: stage x -> A hi/lo (swizzled) ----
    for (int k = 0; k < 4; ++k) {
        const int si = tid + k * 512;          // 0..2047 slot-pairs
        const int t  = si >> 5;
        const int s  = si & 31;
        const float4 v0 = *(const float4*)(x + (tok0 + t) * 256 + s * 8);
        const float4 v1 = *(const float4*)(x + (tok0 + t) * 256 + s * 8 + 4);
        const float vv[8] = {v0.x, v0.y, v0.z, v0.w, v1.x, v1.y, v1.z, v1.w};
        f16x8 h8, l8;
#pragma unroll
        for (int e = 0; e < 8; ++e) {
            const _Float16 hi = (_Float16)vv[e];
            h8[e] = hi;
            l8[e] = (_Float16)(vv[e] - (float)hi);
        }
        const int ss = s ^ (t & 31);
        ((f16x8*)(Ahi + t * 256))[ss] = h8;
        ((f16x8*)(Alo + t * 256))[ss] = l8;
    }

    // ---- Layer loop ----
    for (int q = 0; q < NQ; ++q) {
        f32x16 acc[2][4];
#pragma unroll
        for (int rt = 0; rt < 2; ++rt)
#pragma unroll
            for (int ct = 0; ct < 4; ++ct)
#pragma unroll
                for (int r = 0; r < 16; ++r) acc[rt][ct][r] = 0.f;

        const char* gBq = (const char*)(embedB + q * 524288);  // bytes into layer

        for (int c = 0; c < 16; ++c) {
            __syncthreads();   // previous chunk fully consumed / scratch safe
            // stage B chunk (64 KB) via global->LDS DMA, width 16
            {
                const char* gB = gBq + c * 65536;
#pragma unroll
                for (int r = 0; r < 8; ++r) {
                    const void* gp = gB + r * 8192 + tid * 16;          // per-lane
                    void* lp = smem + 65536 + r * 8192 + wave * 1024;   // wave-uniform
                    __builtin_amdgcn_global_load_lds((const AS1 uint32_t*)gp,
                                                     (AS3 uint32_t*)lp, 16, 0, 0);
                }
            }
            __syncthreads();   // drains vmcnt: B chunk visible

            // A fragments (token rows), B fragments (code rows)
            f16x8 aH[2], aL[2];
#pragma unroll
            for (int rt = 0; rt < 2; ++rt) {
                const int t  = rt * 32 + l32;
                const int sa = (2 * c + h32) ^ (t & 31);
                aH[rt] = ((const f16x8*)(Ahi + t * 256))[sa];
                aL[rt] = ((const f16x8*)(Alo + t * 256))[sa];
            }
            f16x8 bH[4], bL[4];
#pragma unroll
            for (int ct = 0; ct < 4; ++ct) {
                const int cf = codeBase + ct * 32 + l32;
                const int g  = cf >> 2;
                const int slot = g * 8 + ((((cf << 1) + h32) & 7) ^ (g & 7));
                bH[ct] = ((const f16x8*)(smem + 65536))[slot];
                bL[ct] = ((const f16x8*)(smem + 65536 + 32768))[slot];
            }
#pragma unroll
            for (int rt = 0; rt < 2; ++rt)
#pragma unroll
                for (int ct = 0; ct < 4; ++ct) {
                    acc[rt][ct] = __builtin_amdgcn_mfma_f32_32x32x16_f16(
                        aH[rt], bH[ct], acc[rt][ct], 0, 0, 0);
                    acc[rt][ct] = __builtin_amdgcn_mfma_f32_32x32x16_f16(
                        aH[rt], bL[ct], acc[rt][ct], 0, 0, 0);
                    acc[rt][ct] = __builtin_amdgcn_mfma_f32_32x32x16_f16(
                        aL[rt], bH[ct], acc[rt][ct], 0, 0, 0);
                }
        }

        // ---- scores + per-wave argmin ----
        float e2v[4];
#pragma unroll
        for (int ct = 0; ct < 4; ++ct)
            e2v[ct] = e2g[q * 1024 + codeBase + ct * 32 + l32];

#pragma unroll
        for (int rt = 0; rt < 2; ++rt) {
#pragma unroll
            for (int r = 0; r < 16; ++r) {
                float bs = 3.4e38f;
                int   bi = 0x7fffffff;
#pragma unroll
                for (int ct = 0; ct < 4; ++ct) {
                    const float sc = e2v[ct] - 2.0f * acc[rt][ct][r];
                    const int   cd = codeBase + ct * 32 + l32;
                    if (sc < bs || (sc == bs && cd < bi)) { bs = sc; bi = cd; }
                }
                // lexicographic min over the 32 lanes of this half
#pragma unroll
                for (int m = 1; m < 32; m <<= 1) {
                    const float so = __shfl_xor(bs, m);
                    const int   io = __shfl_xor(bi, m);
                    if (so < bs || (so == bs && io < bi)) { bs = so; bi = io; }
                }
                if (l32 == 0) {
                    const int row = rt * 32 + (r & 3) + 8 * (r >> 2) + 4 * h32;
                    bestS[wave * 64 + row] = bs;
                    bestI[wave * 64 + row] = bi;
                }
            }
        }
        __syncthreads();

        // ---- cross-wave argmin (waves cover ascending code ranges) ----
        if (tid < 64) {
            float bs = bestS[tid];
            int   bi = bestI[tid];
            for (int w = 1; w < 8; ++w) {
                const float s2 = bestS[w * 64 + tid];
                const int   i2 = bestI[w * 64 + tid];
                if (s2 < bs || (s2 == bs && i2 < bi)) { bs = s2; bi = i2; }
            }
            indF[tid] = bi;
            atomicAdd(&counts[q * 1024 + bi], 1);
        }
        __syncthreads();

        // ---- update: r -= quantize; loss partial; residual back to hi/lo ----
        {
            const int tl = tid >> 3;          // token 0..63
            const int sg = tid & 7;           // 32-dim strip
            const int csel = indF[tl];
            const float* gq = embedT + (q * 1024 + csel) * 256 + sg * 32;
            float lp = 0.f;
            f16x8* rowH = (f16x8*)(Ahi + tl * 256);
            f16x8* rowL = (f16x8*)(Alo + tl * 256);
#pragma unroll
            for (int it = 0; it < 4; ++it) {
                const int slot = (sg * 4 + it) ^ (tl & 31);
                f16x8 h8 = rowH[slot];
                f16x8 l8 = rowL[slot];
                const float4 q0 = *(const float4*)(gq + it * 8);
                const float4 q1 = *(const float4*)(gq + it * 8 + 4);
                const float qv[8] = {q0.x, q0.y, q0.z, q0.w, q1.x, q1.y, q1.z, q1.w};
#pragma unroll
                for (int e = 0; e < 8; ++e) {
                    const float rv = (float)h8[e] + (float)l8[e];
                    const float nr = rv - qv[e];
                    lp += nr * nr;
                    const _Float16 nh = (_Float16)nr;
                    h8[e] = nh;
                    l8[e] = (_Float16)(nr - (float)nh);
                }
                rowH[slot] = h8;
                rowL[slot] = l8;
            }
            // loss reduction: wave -> block -> global atomic
#pragma unroll
            for (int off = 32; off > 0; off >>= 1) lp += __shfl_down(lp, off);
            if (lane == 0) lossRed[wave] = lp;
        }
        __syncthreads();
        if (tid == 0) {
            float t = 0.f;
            for (int w = 0; w < 8; ++w) t += lossRed[w];
            atomicAdd(&lossSum[q], t);
        }
        // next layer's chunk-0 __syncthreads protects lossRed / A-tile
    }

    __syncthreads();
    // ---- epilogue: quantized_out = x - residual_final ----
    for (int k = 0; k < 4; ++k) {
        const int si = tid + k * 512;
        const int t  = si >> 5;
        const int s  = si & 31;
        const float* gx = x + (tok0 + t) * 256 + s * 8;
        const int ss = s ^ (t & 31);
        const f16x8 h8 = ((const f16x8*)(Ahi + t * 256))[ss];
        const f16x8 l8 = ((const f16x8*)(Alo + t * 256))[ss];
        float4 o0, o1;
        o0.x = gx[0] - ((float)h8[0] + (float)l8[0]);
        o0.y = gx[1] - ((float)h8[1] + (float)l8[1]);
        o0.z = gx[2] - ((float)h8[2] + (float)l8[2]);
        o0.w = gx[3] - ((float)h8[3] + (float)l8[3]);
        o1.x = gx[4] - ((float)h8[4] + (float)l8[4]);
        o1.y = gx[5] - ((float)h8[5] + (float)l8[5]);
        o1.z = gx[6] - ((float)h8[6] + (float)l8[6]);
        o1.w = gx[7] - ((float)h8[7] + (float)l8[7]);
        *(float4*)(out + (tok0 + t) * 256 + s * 8)     = o0;
        *(float4*)(out + (tok0 + t) * 256 + s * 8 + 4) = o1;
    }
}

// ---------------------------------------------------------------------------
// Finalize: losses + perplexities into the output tail.
// ---------------------------------------------------------------------------
__global__ __launch_bounds__(256)
void vq_finalize(const int* __restrict__ counts, const float* __restrict__ lossSum,
                 float* __restrict__ outTail) {
    const int q = blockIdx.x;
    const int tid = threadIdx.x;
    float s = 0.f;
    for (int k = tid; k < KCODES; k += 256) {
        const float p = (float)counts[q * KCODES + k] * (1.0f / 65536.0f);
        s += p * logf(p + 1e-10f);
    }
    for (int off = 32; off > 0; off >>= 1) s += __shfl_down(s, off);
    __shared__ float wpart[4];
    if ((tid & 63) == 0) wpart[tid >> 6] = s;
    __syncthreads();
    if (tid == 0) {
        outTail[q]     = lossSum[q] * (1.0f / 16777216.0f);   // mean * COMMITMENT
        outTail[8 + q] = expf(-(wpart[0] + wpart[1] + wpart[2] + wpart[3]));
    }
}

// ---------------------------------------------------------------------------
extern "C" void kernel_launch(void* const* d_in, const int* in_sizes, int n_in,
                              void* d_out, int out_size, void* d_ws, size_t ws_size,
                              hipStream_t stream) {
    const float* x      = (const float*)d_in[0];   // [32,2048,256]
    const float* embeds = (const float*)d_in[1];   // [8,256,1024]
    float* out = (float*)d_out;                    // 16777216 + 8 + 8

    // Workspace layout (float units unless noted):
    float* embedT = (float*)d_ws;                       // 2,097,152
    float* e2     = embedT + 2097152;                   // 8,192
    float* lossSum = e2 + 8192;                         // 8
    int*   counts  = (int*)(lossSum + 8);               // 8,192
    _Float16* embedB = (_Float16*)(counts + 8192);      // 4,194,304 halfs (8 MB)

    hipMemsetAsync(lossSum, 0, (8 + 8192) * sizeof(float), stream);

    vq_transpose<<<8192, 256, 0, stream>>>(embeds, embedT);
    vq_e2<<<32, 256, 0, stream>>>(embeds, e2);
    vq_embedB<<<8192, 256, 0, stream>>>(embeds, embedB);

    static int ldsSet = 0;
    (void)ldsSet;
    hipFuncSetAttribute((const void*)vq_fused,
                        hipFuncAttributeMaxDynamicSharedMemorySize, LDS_BYTES);
    vq_fused<<<NTOK / TOKPB, 512, LDS_BYTES, stream>>>(
        x, embedT, e2, embedB, out, lossSum, counts);

    vq_finalize<<<NQ, 256, 0, stream>>>(counts, lossSum, out + NELEM);
}

// Round 3
// 2037.003 us; speedup vs baseline: 2.5405x; 1.0305x over previous
//
#include <hip/hip_runtime.h>
#include <hip/hip_bf16.h>
#include <math.h>
#include <stdint.h>

// Problem constants
#define NQ 8
#define DIMV 256
#define KCODES 1024
#define NTOK 65536              // 32*2048
#define NELEM (NTOK * DIMV)     // 16777216
#define TOKPB 64                // tokens per block in fused kernel

typedef _Float16 f16x8 __attribute__((ext_vector_type(8)));
typedef float    f32x16 __attribute__((ext_vector_type(16)));

#define AS3 __attribute__((address_space(3)))
#define AS1 __attribute__((address_space(1)))

// s_waitcnt immediates (gfx9 encoding: vmcnt[3:0]|expcnt[6:4]|lgkmcnt[11:8]|vmcnt_hi[15:14])
#define WAIT_VM0   0x0F70   // vmcnt(0), expcnt/lgkmcnt unconstrained
#define WAIT_LGKM0 0xC07F   // lgkmcnt(0), vmcnt/expcnt unconstrained

// rotate-left-3 of a 5-bit slot index (bijective bank-spreading permutation)
__device__ __forceinline__ int rotl3(int s) { return ((s << 3) | (s >> 2)) & 31; }

// ---------------------------------------------------------------------------
// Pre-pass 1: transpose embeds [q][d][k] -> embedT [q][k][d] (fp32, for the
// quantize gather in the update phase).
// ---------------------------------------------------------------------------
__global__ __launch_bounds__(256)
void vq_transpose(const float* __restrict__ embeds, float* __restrict__ embedT) {
    const int idx = blockIdx.x * 256 + threadIdx.x;       // 0 .. 2097151
    const int q   = idx >> 18;
    const int rem = idx & 262143;
    const int k   = rem >> 8;
    const int d   = rem & 255;
    embedT[idx] = embeds[q * 262144 + d * 1024 + k];
}

// Pre-pass 2: e2[q][k] = sum_d embed[q][d][k]^2 (fp32)
__global__ __launch_bounds__(256)
void vq_e2(const float* __restrict__ embeds, float* __restrict__ e2) {
    const int idx = blockIdx.x * 256 + threadIdx.x;       // 0 .. 8191
    const int q = idx >> 10;
    const int k = idx & 1023;
    const float* e = embeds + q * 262144 + k;
    float s = 0.f;
    for (int d = 0; d < DIMV; ++d) {
        const float v = e[d * 1024];
        s += v * v;
    }
    e2[idx] = s;
}

// ---------------------------------------------------------------------------
// Pre-pass 3: split embed into fp16 hi/lo laid out as per-(layer,chunk,wave)
// 8 KB images, verbatim what the fused kernel DMAs into LDS:
//   embedB[q][chunk(16)][w(8)][part(2)][s(256)][j(8)]   (halfs)
// s = h*128 + cl  (h = k-half of chunk, cl = code within wave's 128)
// d = chunk*16 + h*8 + j ;  k = w*128 + cl
// Fragment read then is: lane(l32,h32), tile ct -> s = h32*128+ct*32+l32
// (consecutive lanes -> consecutive 16B slots: conflict-free).
// ---------------------------------------------------------------------------
__global__ __launch_bounds__(256)
void vq_embedB(const float* __restrict__ embeds, _Float16* __restrict__ embedB) {
    const int idx = blockIdx.x * 256 + threadIdx.x;       // 0 .. 4194303
    const int j    = idx & 7;
    const int s    = (idx >> 3) & 255;
    const int part = (idx >> 11) & 1;
    const int w    = (idx >> 12) & 7;
    const int c    = (idx >> 15) & 15;
    const int q    = idx >> 19;
    const int h  = s >> 7;
    const int cl = s & 127;
    const int d  = c * 16 + h * 8 + j;
    const int k  = w * 128 + cl;
    const float v = embeds[q * 262144 + d * 1024 + k];
    const _Float16 hi = (_Float16)v;
    embedB[idx] = (part == 0) ? hi : (_Float16)(v - (float)hi);
}

// ---------------------------------------------------------------------------
// Fused residual-VQ kernel: 1024 blocks x 512 threads, 64 tokens/block.
// Residual kept in LDS as fp16 hi/lo across all 8 layers.
// Distances via 3-pass fp16 MFMA (hi*Hi + hi*Lo + lo*Hi), fp32 accumulate.
// K-loop has NO block barriers: each wave DMAs its own 8 KB B slice into a
// private LDS region and self-syncs with per-wave s_waitcnt.
// ---------------------------------------------------------------------------
// LDS layout (bytes):
//  [0,      32768)  A_hi : 64 rows x 256 d fp16; 16B-block s of row t stored
//                          at slot rotl3(s)^(t&31)
//  [32768,  65536)  A_lo : same layout
//  [65536, 131072)  B wave regions: wave w at 65536+w*8192,
//                          [part(2)][s(256)][16B] verbatim embedB image
//  [131072,133120)  bestS  float[8][64]
//  [133120,135168)  bestI  int  [8][64]
//  [135168,135424)  indF   int  [64]
//  [135424,135456)  lossRed float[8]
#define LDS_BYTES 135456

__global__ __launch_bounds__(512, 2)
void vq_fused(const float* __restrict__ x, const float* __restrict__ embedT,
              const float* __restrict__ e2g, const _Float16* __restrict__ embedB,
              float* __restrict__ out, float* __restrict__ lossSum,
              int* __restrict__ counts) {
    extern __shared__ char smem[];
    _Float16* Ahi = (_Float16*)smem;
    _Float16* Alo = (_Float16*)(smem + 32768);
    float* bestS   = (float*)(smem + 131072);
    int*   bestI   = (int*)(smem + 133120);
    int*   indF    = (int*)(smem + 135168);
    float* lossRed = (float*)(smem + 135424);

    const int tid    = threadIdx.x;
    const int wave   = tid >> 6;
    const int lane   = tid & 63;
    const int l32    = lane & 31;
    const int h32    = lane >> 5;
    const int tok0   = blockIdx.x * TOKPB;
    const int codeBase = wave * 128;
    char* Bw = smem + 65536 + wave * 8192;     // this wave's private B region

    // ---- Phase 0: stage x -> A hi/lo (swizzled) ----
    for (int k = 0; k < 4; ++k) {
        const int si = tid + k * 512;          // 0..2047 (t,s) pairs
        const int t  = si >> 5;
        const int s  = si & 31;
        const float4 v0 = *(const float4*)(x + (tok0 + t) * 256 + s * 8);
        const float4 v1 = *(const float4*)(x + (tok0 + t) * 256 + s * 8 + 4);
        const float vv[8] = {v0.x, v0.y, v0.z, v0.w, v1.x, v1.y, v1.z, v1.w};
        f16x8 h8, l8;
#pragma unroll
        for (int e = 0; e < 8; ++e) {
            const _Float16 hi = (_Float16)vv[e];
            h8[e] = hi;
            l8[e] = (_Float16)(vv[e] - (float)hi);
        }
        const int ss = rotl3(s) ^ (t & 31);
        ((f16x8*)(Ahi + t * 256))[ss] = h8;
        ((f16x8*)(Alo + t * 256))[ss] = l8;
    }
    __syncthreads();

    // ---- Layer loop ----
    for (int q = 0; q < NQ; ++q) {
        f32x16 acc[2][4];
#pragma unroll
        for (int rt = 0; rt < 2; ++rt)
#pragma unroll
            for (int ct = 0; ct < 4; ++ct)
#pragma unroll
                for (int r = 0; r < 16; ++r) acc[rt][ct][r] = 0.f;

        const char* gBq = (const char*)embedB + q * 1048576;   // 1 MB / layer

        for (int c = 0; c < 16; ++c) {
            // Ensure this wave's previous-chunk B reads retired before overwrite.
            __builtin_amdgcn_sched_barrier(0);
            __builtin_amdgcn_s_waitcnt(WAIT_LGKM0);
            // Stage this wave's 8 KB B slice (verbatim image), width-16 DMA.
            {
                const char* gB = gBq + c * 65536 + wave * 8192;
#pragma unroll
                for (int r = 0; r < 8; ++r) {
                    const void* gp = gB + r * 1024 + lane * 16;    // per-lane
                    void* lp = Bw + r * 1024;                      // wave-uniform
                    __builtin_amdgcn_global_load_lds((const AS1 uint32_t*)gp,
                                                     (AS3 uint32_t*)lp, 16, 0, 0);
                }
            }
            // A fragments (independent of the staging in flight)
            f16x8 aH[2], aL[2];
#pragma unroll
            for (int rt = 0; rt < 2; ++rt) {
                const int t  = rt * 32 + l32;
                const int ss = rotl3(2 * c + h32) ^ l32;
                aH[rt] = ((const f16x8*)(Ahi + t * 256))[ss];
                aL[rt] = ((const f16x8*)(Alo + t * 256))[ss];
            }
            // Wait for this wave's DMA, then read B fragments.
            __builtin_amdgcn_s_waitcnt(WAIT_VM0);
            __builtin_amdgcn_sched_barrier(0);
            f16x8 bH[4], bL[4];
#pragma unroll
            for (int ct = 0; ct < 4; ++ct) {
                const int sB = h32 * 128 + ct * 32 + l32;
                bH[ct] = ((const f16x8*)(Bw))[sB];
                bL[ct] = ((const f16x8*)(Bw + 4096))[sB];
            }
#pragma unroll
            for (int rt = 0; rt < 2; ++rt)
#pragma unroll
                for (int ct = 0; ct < 4; ++ct) {
                    acc[rt][ct] = __builtin_amdgcn_mfma_f32_32x32x16_f16(
                        aH[rt], bH[ct], acc[rt][ct], 0, 0, 0);
                    acc[rt][ct] = __builtin_amdgcn_mfma_f32_32x32x16_f16(
                        aH[rt], bL[ct], acc[rt][ct], 0, 0, 0);
                    acc[rt][ct] = __builtin_amdgcn_mfma_f32_32x32x16_f16(
                        aL[rt], bH[ct], acc[rt][ct], 0, 0, 0);
                }
        }

        // ---- scores + per-wave argmin ----
        float e2v[4];
#pragma unroll
        for (int ct = 0; ct < 4; ++ct)
            e2v[ct] = e2g[q * 1024 + codeBase + ct * 32 + l32];

#pragma unroll
        for (int rt = 0; rt < 2; ++rt) {
#pragma unroll
            for (int r = 0; r < 16; ++r) {
                float bs = 3.4e38f;
                int   bi = 0x7fffffff;
#pragma unroll
                for (int ct = 0; ct < 4; ++ct) {
                    const float sc = e2v[ct] - 2.0f * acc[rt][ct][r];
                    const int   cd = codeBase + ct * 32 + l32;
                    if (sc < bs || (sc == bs && cd < bi)) { bs = sc; bi = cd; }
                }
                // lexicographic min over the 32 lanes of this half
#pragma unroll
                for (int m = 1; m < 32; m <<= 1) {
                    const float so = __shfl_xor(bs, m);
                    const int   io = __shfl_xor(bi, m);
                    if (so < bs || (so == bs && io < bi)) { bs = so; bi = io; }
                }
                if (l32 == 0) {
                    const int row = rt * 32 + (r & 3) + 8 * (r >> 2) + 4 * h32;
                    bestS[wave * 64 + row] = bs;
                    bestI[wave * 64 + row] = bi;
                }
            }
        }
        __syncthreads();

        // ---- cross-wave argmin (waves cover ascending code ranges) ----
        if (tid < 64) {
            float bs = bestS[tid];
            int   bi = bestI[tid];
            for (int w = 1; w < 8; ++w) {
                const float s2 = bestS[w * 64 + tid];
                const int   i2 = bestI[w * 64 + tid];
                if (s2 < bs || (s2 == bs && i2 < bi)) { bs = s2; bi = i2; }
            }
            indF[tid] = bi;
            atomicAdd(&counts[q * 1024 + bi], 1);
        }
        __syncthreads();

        // ---- update: r -= quantize; loss partial; residual back to hi/lo ----
        {
            const int tl = tid >> 3;          // token 0..63
            const int sg = tid & 7;           // 32-dim strip
            const int csel = indF[tl];
            const float* gq = embedT + (q * 1024 + csel) * 256 + sg * 32;
            float lp = 0.f;
            f16x8* rowH = (f16x8*)(Ahi + tl * 256);
            f16x8* rowL = (f16x8*)(Alo + tl * 256);
#pragma unroll
            for (int it = 0; it < 4; ++it) {
                const int slot = rotl3(sg * 4 + it) ^ (tl & 31);
                f16x8 h8 = rowH[slot];
                f16x8 l8 = rowL[slot];
                const float4 q0 = *(const float4*)(gq + it * 8);
                const float4 q1 = *(const float4*)(gq + it * 8 + 4);
                const float qv[8] = {q0.x, q0.y, q0.z, q0.w, q1.x, q1.y, q1.z, q1.w};
#pragma unroll
                for (int e = 0; e < 8; ++e) {
                    const float rv = (float)h8[e] + (float)l8[e];
                    const float nr = rv - qv[e];
                    lp += nr * nr;
                    const _Float16 nh = (_Float16)nr;
                    h8[e] = nh;
                    l8[e] = (_Float16)(nr - (float)nh);
                }
                rowH[slot] = h8;
                rowL[slot] = l8;
            }
            // loss reduction: wave -> block -> global atomic
#pragma unroll
            for (int off = 32; off > 0; off >>= 1) lp += __shfl_down(lp, off);
            if (lane == 0) lossRed[wave] = lp;
        }
        __syncthreads();
        if (tid == 0) {
            float t = 0.f;
            for (int w = 0; w < 8; ++w) t += lossRed[w];
            atomicAdd(&lossSum[q], t);
        }
        // A-tile writes are barrier-protected by the __syncthreads above.
    }

    __syncthreads();
    // ---- epilogue: quantized_out = x - residual_final ----
    for (int k = 0; k < 4; ++k) {
        const int si = tid + k * 512;
        const int t  = si >> 5;
        const int s  = si & 31;
        const float* gx = x + (tok0 + t) * 256 + s * 8;
        const int ss = rotl3(s) ^ (t & 31);
        const f16x8 h8 = ((const f16x8*)(Ahi + t * 256))[ss];
        const f16x8 l8 = ((const f16x8*)(Alo + t * 256))[ss];
        float4 o0, o1;
        o0.x = gx[0] - ((float)h8[0] + (float)l8[0]);
        o0.y = gx[1] - ((float)h8[1] + (float)l8[1]);
        o0.z = gx[2] - ((float)h8[2] + (float)l8[2]);
        o0.w = gx[3] - ((float)h8[3] + (float)l8[3]);
        o1.x = gx[4] - ((float)h8[4] + (float)l8[4]);
        o1.y = gx[5] - ((float)h8[5] + (float)l8[5]);
        o1.z = gx[6] - ((float)h8[6] + (float)l8[6]);
        o1.w = gx[7] - ((float)h8[7] + (float)l8[7]);
        *(float4*)(out + (tok0 + t) * 256 + s * 8)     = o0;
        *(float4*)(out + (tok0 + t) * 256 + s * 8 + 4) = o1;
    }
}

// ---------------------------------------------------------------------------
// Finalize: losses + perplexities into the output tail.
// ---------------------------------------------------------------------------
__global__ __launch_bounds__(256)
void vq_finalize(const int* __restrict__ counts, const float* __restrict__ lossSum,
                 float* __restrict__ outTail) {
    const int q = blockIdx.x;
    const int tid = threadIdx.x;
    float s = 0.f;
    for (int k = tid; k < KCODES; k += 256) {
        const float p = (float)counts[q * KCODES + k] * (1.0f / 65536.0f);
        s += p * logf(p + 1e-10f);
    }
    for (int off = 32; off > 0; off >>= 1) s += __shfl_down(s, off);
    __shared__ float wpart[4];
    if ((tid & 63) == 0) wpart[tid >> 6] = s;
    __syncthreads();
    if (tid == 0) {
        outTail[q]     = lossSum[q] * (1.0f / 16777216.0f);   // mean * COMMITMENT
        outTail[8 + q] = expf(-(wpart[0] + wpart[1] + wpart[2] + wpart[3]));
    }
}

// ---------------------------------------------------------------------------
extern "C" void kernel_launch(void* const* d_in, const int* in_sizes, int n_in,
                              void* d_out, int out_size, void* d_ws, size_t ws_size,
                              hipStream_t stream) {
    const float* x      = (const float*)d_in[0];   // [32,2048,256]
    const float* embeds = (const float*)d_in[1];   // [8,256,1024]
    float* out = (float*)d_out;                    // 16777216 + 8 + 8

    // Workspace layout (float units unless noted):
    float* embedT = (float*)d_ws;                       // 2,097,152
    float* e2     = embedT + 2097152;                   // 8,192
    float* lossSum = e2 + 8192;                         // 8
    int*   counts  = (int*)(lossSum + 8);               // 8,192
    _Float16* embedB = (_Float16*)(counts + 8192);      // 4,194,304 halfs (8 MB)

    hipMemsetAsync(lossSum, 0, (8 + 8192) * sizeof(float), stream);

    vq_transpose<<<8192, 256, 0, stream>>>(embeds, embedT);
    vq_e2<<<32, 256, 0, stream>>>(embeds, e2);
    vq_embedB<<<16384, 256, 0, stream>>>(embeds, embedB);

    hipFuncSetAttribute((const void*)vq_fused,
                        hipFuncAttributeMaxDynamicSharedMemorySize, LDS_BYTES);
    vq_fused<<<NTOK / TOKPB, 512, LDS_BYTES, stream>>>(
        x, embedT, e2, embedB, out, lossSum, counts);

    vq_finalize<<<NQ, 256, 0, stream>>>(counts, lossSum, out + NELEM);
}

// Round 4
// 1799.243 us; speedup vs baseline: 2.8762x; 1.1321x over previous
//
#include <hip/hip_runtime.h>
#include <hip/hip_bf16.h>
#include <math.h>
#include <stdint.h>

// Problem constants
#define NQ 8
#define DIMV 256
#define KCODES 1024
#define NTOK 65536              // 32*2048
#define NELEM (NTOK * DIMV)     // 16777216
#define TOKPB 64                // tokens per block in layer kernel

typedef _Float16 f16x8 __attribute__((ext_vector_type(8)));
typedef float    f32x16 __attribute__((ext_vector_type(16)));

#define AS3 __attribute__((address_space(3)))
#define AS1 __attribute__((address_space(1)))

// s_waitcnt immediates (gfx9 encoding: vmcnt[3:0]|expcnt[6:4]|lgkmcnt[11:8]|vmcnt_hi[15:14])
#define WAIT_VM0   0x0F70   // vmcnt(0), expcnt/lgkmcnt unconstrained
#define WAIT_LGKM0 0xC07F   // lgkmcnt(0), vmcnt/expcnt unconstrained

// rotate-left-3 of a 5-bit slot index (bijective bank-spreading permutation)
__device__ __forceinline__ int rotl3(int s) { return ((s << 3) | (s >> 2)) & 31; }

// ---------------------------------------------------------------------------
// Pre-pass 1: transpose embeds [q][d][k] -> embedT [q][k][d] (fp32, for the
// quantize gather in the update phase).
// ---------------------------------------------------------------------------
__global__ __launch_bounds__(256)
void vq_transpose(const float* __restrict__ embeds, float* __restrict__ embedT) {
    const int idx = blockIdx.x * 256 + threadIdx.x;       // 0 .. 2097151
    const int q   = idx >> 18;
    const int rem = idx & 262143;
    const int k   = rem >> 8;
    const int d   = rem & 255;
    embedT[idx] = embeds[q * 262144 + d * 1024 + k];
}

// Pre-pass 2: e2[q][k] = sum_d embed[q][d][k]^2 (fp32)
__global__ __launch_bounds__(256)
void vq_e2(const float* __restrict__ embeds, float* __restrict__ e2) {
    const int idx = blockIdx.x * 256 + threadIdx.x;       // 0 .. 8191
    const int q = idx >> 10;
    const int k = idx & 1023;
    const float* e = embeds + q * 262144 + k;
    float s = 0.f;
    for (int d = 0; d < DIMV; ++d) {
        const float v = e[d * 1024];
        s += v * v;
    }
    e2[idx] = s;
}

// ---------------------------------------------------------------------------
// Pre-pass 3: split embed into fp16 hi/lo laid out as per-(layer,chunk,wave)
// 8 KB images, verbatim what the layer kernel DMAs into LDS:
//   embedB[q][chunk(16)][w(8)][part(2)][s(256)][j(8)]   (halfs)
// s = h*128 + cl ; d = chunk*16 + h*8 + j ; k = w*128 + cl
// ---------------------------------------------------------------------------
__global__ __launch_bounds__(256)
void vq_embedB(const float* __restrict__ embeds, _Float16* __restrict__ embedB) {
    const int idx = blockIdx.x * 256 + threadIdx.x;       // 0 .. 4194303
    const int j    = idx & 7;
    const int s    = (idx >> 3) & 255;
    const int part = (idx >> 11) & 1;
    const int w    = (idx >> 12) & 7;
    const int c    = (idx >> 15) & 15;
    const int q    = idx >> 19;
    const int h  = s >> 7;
    const int cl = s & 127;
    const int d  = c * 16 + h * 8 + j;
    const int k  = w * 128 + cl;
    const float v = embeds[q * 262144 + d * 1024 + k];
    const _Float16 hi = (_Float16)v;
    embedB[idx] = (part == 0) ? hi : (_Float16)(v - (float)hi);
}

// ---------------------------------------------------------------------------
// Per-layer VQ kernel: 1024 blocks x 512 threads, 64 tokens/block.
// Reads fp32 residual (or x) from global, finds argmin code via 3-pass fp16
// MFMA, updates residual in place, accumulates loss + counts.
// The 1 MB per-layer split-B is shared by every block -> L2-resident.
// ---------------------------------------------------------------------------
// LDS layout (bytes):
//  [0,      32768)  A_hi : 64 rows x 256 d fp16; 16B-block s of row t at
//                          slot rotl3(s)^(t&31)
//  [32768,  65536)  A_lo : same layout
//  [65536, 131072)  B wave regions: wave w at 65536+w*8192,
//                          [part(2)][s(256)][16B] verbatim embedB image
//  [131072,133120)  bestS  float[8][64]
//  [133120,135168)  bestI  int  [8][64]
//  [135168,135424)  indF   int  [64]
//  [135424,135456)  lossRed float[8]
#define LDS_BYTES 135456

__global__ __launch_bounds__(512, 2)
void vq_layer(const float* __restrict__ resIn, float* __restrict__ resOut,
              const float* __restrict__ embedTq, const float* __restrict__ e2q,
              const _Float16* __restrict__ embedBq, float* __restrict__ lossSumQ,
              int* __restrict__ countsQ) {
    extern __shared__ char smem[];
    _Float16* Ahi = (_Float16*)smem;
    _Float16* Alo = (_Float16*)(smem + 32768);
    float* bestS   = (float*)(smem + 131072);
    int*   bestI   = (int*)(smem + 133120);
    int*   indF    = (int*)(smem + 135168);
    float* lossRed = (float*)(smem + 135424);

    const int tid    = threadIdx.x;
    const int wave   = tid >> 6;
    const int lane   = tid & 63;
    const int l32    = lane & 31;
    const int h32    = lane >> 5;
    const int tok0   = blockIdx.x * TOKPB;
    const int codeBase = wave * 128;
    char* Bw = smem + 65536 + wave * 8192;     // this wave's private B region

    // ---- Phase 0: stage residual -> A hi/lo (swizzled) ----
    for (int k = 0; k < 4; ++k) {
        const int si = tid + k * 512;          // 0..2047 (t,s) pairs
        const int t  = si >> 5;
        const int s  = si & 31;
        const float4 v0 = *(const float4*)(resIn + (tok0 + t) * 256 + s * 8);
        const float4 v1 = *(const float4*)(resIn + (tok0 + t) * 256 + s * 8 + 4);
        const float vv[8] = {v0.x, v0.y, v0.z, v0.w, v1.x, v1.y, v1.z, v1.w};
        f16x8 h8, l8;
#pragma unroll
        for (int e = 0; e < 8; ++e) {
            const _Float16 hi = (_Float16)vv[e];
            h8[e] = hi;
            l8[e] = (_Float16)(vv[e] - (float)hi);
        }
        const int ss = rotl3(s) ^ (t & 31);
        ((f16x8*)(Ahi + t * 256))[ss] = h8;
        ((f16x8*)(Alo + t * 256))[ss] = l8;
    }
    __syncthreads();

    // ---- K-loop: barrier-free, wave-private B staging ----
    f32x16 acc[2][4];
#pragma unroll
    for (int rt = 0; rt < 2; ++rt)
#pragma unroll
        for (int ct = 0; ct < 4; ++ct)
#pragma unroll
            for (int r = 0; r < 16; ++r) acc[rt][ct][r] = 0.f;

    for (int c = 0; c < 16; ++c) {
        // Ensure this wave's previous-chunk B reads retired before overwrite.
        __builtin_amdgcn_sched_barrier(0);
        __builtin_amdgcn_s_waitcnt(WAIT_LGKM0);
        // Stage this wave's 8 KB B slice (verbatim image), width-16 DMA.
        {
            const char* gB = (const char*)embedBq + c * 65536 + wave * 8192;
#pragma unroll
            for (int r = 0; r < 8; ++r) {
                const void* gp = gB + r * 1024 + lane * 16;    // per-lane
                void* lp = Bw + r * 1024;                      // wave-uniform
                __builtin_amdgcn_global_load_lds((const AS1 uint32_t*)gp,
                                                 (AS3 uint32_t*)lp, 16, 0, 0);
            }
        }
        // A fragments (independent of the staging in flight)
        f16x8 aH[2], aL[2];
#pragma unroll
        for (int rt = 0; rt < 2; ++rt) {
            const int t  = rt * 32 + l32;
            const int ss = rotl3(2 * c + h32) ^ l32;
            aH[rt] = ((const f16x8*)(Ahi + t * 256))[ss];
            aL[rt] = ((const f16x8*)(Alo + t * 256))[ss];
        }
        // Wait for this wave's DMA, then read B fragments.
        __builtin_amdgcn_s_waitcnt(WAIT_VM0);
        __builtin_amdgcn_sched_barrier(0);
        f16x8 bH[4], bL[4];
#pragma unroll
        for (int ct = 0; ct < 4; ++ct) {
            const int sB = h32 * 128 + ct * 32 + l32;
            bH[ct] = ((const f16x8*)(Bw))[sB];
            bL[ct] = ((const f16x8*)(Bw + 4096))[sB];
        }
#pragma unroll
        for (int rt = 0; rt < 2; ++rt)
#pragma unroll
            for (int ct = 0; ct < 4; ++ct) {
                acc[rt][ct] = __builtin_amdgcn_mfma_f32_32x32x16_f16(
                    aH[rt], bH[ct], acc[rt][ct], 0, 0, 0);
                acc[rt][ct] = __builtin_amdgcn_mfma_f32_32x32x16_f16(
                    aH[rt], bL[ct], acc[rt][ct], 0, 0, 0);
                acc[rt][ct] = __builtin_amdgcn_mfma_f32_32x32x16_f16(
                    aL[rt], bH[ct], acc[rt][ct], 0, 0, 0);
            }
    }

    // ---- scores + per-wave argmin ----
    float e2v[4];
#pragma unroll
    for (int ct = 0; ct < 4; ++ct)
        e2v[ct] = e2q[codeBase + ct * 32 + l32];

#pragma unroll
    for (int rt = 0; rt < 2; ++rt) {
#pragma unroll
        for (int r = 0; r < 16; ++r) {
            float bs = 3.4e38f;
            int   bi = 0x7fffffff;
#pragma unroll
            for (int ct = 0; ct < 4; ++ct) {
                const float sc = e2v[ct] - 2.0f * acc[rt][ct][r];
                const int   cd = codeBase + ct * 32 + l32;
                if (sc < bs || (sc == bs && cd < bi)) { bs = sc; bi = cd; }
            }
            // lexicographic min over the 32 lanes of this half
#pragma unroll
            for (int m = 1; m < 32; m <<= 1) {
                const float so = __shfl_xor(bs, m);
                const int   io = __shfl_xor(bi, m);
                if (so < bs || (so == bs && io < bi)) { bs = so; bi = io; }
            }
            if (l32 == 0) {
                const int row = rt * 32 + (r & 3) + 8 * (r >> 2) + 4 * h32;
                bestS[wave * 64 + row] = bs;
                bestI[wave * 64 + row] = bi;
            }
        }
    }
    __syncthreads();

    // ---- cross-wave argmin (waves cover ascending code ranges) ----
    if (tid < 64) {
        float bs = bestS[tid];
        int   bi = bestI[tid];
        for (int w = 1; w < 8; ++w) {
            const float s2 = bestS[w * 64 + tid];
            const int   i2 = bestI[w * 64 + tid];
            if (s2 < bs || (s2 == bs && i2 < bi)) { bs = s2; bi = i2; }
        }
        indF[tid] = bi;
        atomicAdd(&countsQ[bi], 1);
    }
    __syncthreads();

    // ---- update: r -= quantize (into LDS); loss partial ----
    {
        const int tl = tid >> 3;          // token 0..63
        const int sg = tid & 7;           // 32-dim strip
        const int csel = indF[tl];
        const float* gq = embedTq + csel * 256 + sg * 32;
        float lp = 0.f;
        f16x8* rowH = (f16x8*)(Ahi + tl * 256);
        f16x8* rowL = (f16x8*)(Alo + tl * 256);
#pragma unroll
        for (int it = 0; it < 4; ++it) {
            const int slot = rotl3(sg * 4 + it) ^ (tl & 31);
            f16x8 h8 = rowH[slot];
            f16x8 l8 = rowL[slot];
            const float4 q0 = *(const float4*)(gq + it * 8);
            const float4 q1 = *(const float4*)(gq + it * 8 + 4);
            const float qv[8] = {q0.x, q0.y, q0.z, q0.w, q1.x, q1.y, q1.z, q1.w};
#pragma unroll
            for (int e = 0; e < 8; ++e) {
                const float rv = (float)h8[e] + (float)l8[e];
                const float nr = rv - qv[e];
                lp += nr * nr;
                const _Float16 nh = (_Float16)nr;
                h8[e] = nh;
                l8[e] = (_Float16)(nr - (float)nh);
            }
            rowH[slot] = h8;
            rowL[slot] = l8;
        }
        // loss reduction: wave -> block -> global atomic
#pragma unroll
        for (int off = 32; off > 0; off >>= 1) lp += __shfl_down(lp, off);
        if (lane == 0) lossRed[wave] = lp;
    }
    __syncthreads();
    if (tid == 0) {
        float t = 0.f;
        for (int w = 0; w < 8; ++w) t += lossRed[w];
        atomicAdd(lossSumQ, t);
    }
    __syncthreads();

    // ---- writeback: new fp32 residual, coalesced ----
    for (int k = 0; k < 4; ++k) {
        const int si = tid + k * 512;
        const int t  = si >> 5;
        const int s  = si & 31;
        const int ss = rotl3(s) ^ (t & 31);
        const f16x8 h8 = ((const f16x8*)(Ahi + t * 256))[ss];
        const f16x8 l8 = ((const f16x8*)(Alo + t * 256))[ss];
        float4 o0, o1;
        o0.x = (float)h8[0] + (float)l8[0];
        o0.y = (float)h8[1] + (float)l8[1];
        o0.z = (float)h8[2] + (float)l8[2];
        o0.w = (float)h8[3] + (float)l8[3];
        o1.x = (float)h8[4] + (float)l8[4];
        o1.y = (float)h8[5] + (float)l8[5];
        o1.z = (float)h8[6] + (float)l8[6];
        o1.w = (float)h8[7] + (float)l8[7];
        *(float4*)(resOut + (tok0 + t) * 256 + s * 8)     = o0;
        *(float4*)(resOut + (tok0 + t) * 256 + s * 8 + 4) = o1;
    }
}

// ---------------------------------------------------------------------------
// Epilogue: quantized_out = x - residual_final
// ---------------------------------------------------------------------------
__global__ __launch_bounds__(256)
void vq_out(const float* __restrict__ x, const float* __restrict__ residual,
            float* __restrict__ out) {
    const int i = blockIdx.x * 256 + threadIdx.x;     // float4 index
    const float4 xv = *(const float4*)(x + i * 4);
    const float4 rv = *(const float4*)(residual + i * 4);
    float4 o;
    o.x = xv.x - rv.x; o.y = xv.y - rv.y; o.z = xv.z - rv.z; o.w = xv.w - rv.w;
    *(float4*)(out + i * 4) = o;
}

// ---------------------------------------------------------------------------
// Finalize: losses + perplexities into the output tail.
// ---------------------------------------------------------------------------
__global__ __launch_bounds__(256)
void vq_finalize(const int* __restrict__ counts, const float* __restrict__ lossSum,
                 float* __restrict__ outTail) {
    const int q = blockIdx.x;
    const int tid = threadIdx.x;
    float s = 0.f;
    for (int k = tid; k < KCODES; k += 256) {
        const float p = (float)counts[q * KCODES + k] * (1.0f / 65536.0f);
        s += p * logf(p + 1e-10f);
    }
    for (int off = 32; off > 0; off >>= 1) s += __shfl_down(s, off);
    __shared__ float wpart[4];
    if ((tid & 63) == 0) wpart[tid >> 6] = s;
    __syncthreads();
    if (tid == 0) {
        outTail[q]     = lossSum[q] * (1.0f / 16777216.0f);   // mean * COMMITMENT
        outTail[8 + q] = expf(-(wpart[0] + wpart[1] + wpart[2] + wpart[3]));
    }
}

// ---------------------------------------------------------------------------
extern "C" void kernel_launch(void* const* d_in, const int* in_sizes, int n_in,
                              void* d_out, int out_size, void* d_ws, size_t ws_size,
                              hipStream_t stream) {
    const float* x      = (const float*)d_in[0];   // [32,2048,256]
    const float* embeds = (const float*)d_in[1];   // [8,256,1024]
    float* out = (float*)d_out;                    // 16777216 + 8 + 8

    // Workspace layout (float units unless noted):
    float* residual = (float*)d_ws;                     // 16,777,216
    float* embedT   = residual + NELEM;                 // 2,097,152
    float* e2       = embedT + 2097152;                 // 8,192
    float* lossSum  = e2 + 8192;                        // 8
    int*   counts   = (int*)(lossSum + 8);              // 8,192
    _Float16* embedB = (_Float16*)(counts + 8192);      // 4,194,304 halfs (8 MB)

    hipMemsetAsync(lossSum, 0, (8 + 8192) * sizeof(float), stream);

    vq_transpose<<<8192, 256, 0, stream>>>(embeds, embedT);
    vq_e2<<<32, 256, 0, stream>>>(embeds, e2);
    vq_embedB<<<16384, 256, 0, stream>>>(embeds, embedB);

    hipFuncSetAttribute((const void*)vq_layer,
                        hipFuncAttributeMaxDynamicSharedMemorySize, LDS_BYTES);
    for (int q = 0; q < NQ; ++q) {
        const float* resIn = (q == 0) ? x : residual;
        vq_layer<<<NTOK / TOKPB, 512, LDS_BYTES, stream>>>(
            resIn, residual,
            embedT + q * (KCODES * DIMV), e2 + q * KCODES,
            embedB + q * 524288, lossSum + q, counts + q * KCODES);
    }

    vq_out<<<NELEM / 4 / 256, 256, 0, stream>>>(x, residual, out);
    vq_finalize<<<NQ, 256, 0, stream>>>(counts, lossSum, out + NELEM);
}

// Round 5
// 1703.074 us; speedup vs baseline: 3.0387x; 1.0565x over previous
//
#include <hip/hip_runtime.h>
#include <hip/hip_bf16.h>
#include <math.h>
#include <stdint.h>

// Problem constants
#define NQ 8
#define DIMV 256
#define KCODES 1024
#define NTOK 65536              // 32*2048
#define NELEM (NTOK * DIMV)     // 16777216
#define TOKPB 64                // tokens per block in layer kernel

typedef _Float16 f16x8 __attribute__((ext_vector_type(8)));
typedef float    f32x16 __attribute__((ext_vector_type(16)));

// rotate-left-3 of a 5-bit slot index (bijective bank-spreading permutation)
__device__ __forceinline__ int rotl3(int s) { return ((s << 3) | (s >> 2)) & 31; }

// ---------------------------------------------------------------------------
// Pre-pass 1: transpose embeds [q][d][k] -> embedT [q][k][d] (fp32, for the
// quantize gather in the update phase).
// ---------------------------------------------------------------------------
__global__ __launch_bounds__(256)
void vq_transpose(const float* __restrict__ embeds, float* __restrict__ embedT) {
    const int idx = blockIdx.x * 256 + threadIdx.x;       // 0 .. 2097151
    const int q   = idx >> 18;
    const int rem = idx & 262143;
    const int k   = rem >> 8;
    const int d   = rem & 255;
    embedT[idx] = embeds[q * 262144 + d * 1024 + k];
}

// Pre-pass 2: e2[q][k] = sum_d embed[q][d][k]^2 (fp32)
__global__ __launch_bounds__(256)
void vq_e2(const float* __restrict__ embeds, float* __restrict__ e2) {
    const int idx = blockIdx.x * 256 + threadIdx.x;       // 0 .. 8191
    const int q = idx >> 10;
    const int k = idx & 1023;
    const float* e = embeds + q * 262144 + k;
    float s = 0.f;
    for (int d = 0; d < DIMV; ++d) {
        const float v = e[d * 1024];
        s += v * v;
    }
    e2[idx] = s;
}

// ---------------------------------------------------------------------------
// Pre-pass 3: split embed into fp16 hi/lo laid out as per-(layer,chunk,range)
// 4 KB images read straight into registers by the layer kernel:
//   embedB[q][chunk(16)][w(16)][part(2)][s(128)][j(8)]   (halfs)
// s = h*64 + cl ; d = chunk*16 + h*8 + j ; k = w*64 + cl
// Fragment read: lane(l32,h32), tile ct -> s = h32*64 + ct*32 + l32
// (lane-contiguous 16B slots -> one coalesced global_load_dwordx4).
// ---------------------------------------------------------------------------
__global__ __launch_bounds__(256)
void vq_embedB(const float* __restrict__ embeds, _Float16* __restrict__ embedB) {
    const int idx = blockIdx.x * 256 + threadIdx.x;       // 0 .. 4194303
    const int j    = idx & 7;
    const int s    = (idx >> 3) & 127;
    const int part = (idx >> 10) & 1;
    const int w    = (idx >> 11) & 15;
    const int c    = (idx >> 15) & 15;
    const int q    = idx >> 19;
    const int h  = s >> 6;
    const int cl = s & 63;
    const int d  = c * 16 + h * 8 + j;
    const int k  = w * 64 + cl;
    const float v = embeds[q * 262144 + d * 1024 + k];
    const _Float16 hi = (_Float16)v;
    embedB[idx] = (part == 0) ? hi : (_Float16)(v - (float)hi);
}

// ---------------------------------------------------------------------------
// Per-layer VQ kernel: 1024 blocks x 1024 threads (16 waves), 64 tokens/block.
// Wave w owns codes [w*64, w*64+64). B is loaded DIRECTLY into registers
// (coalesced dwordx4, depth-1 double-buffered prefetch) -- no LDS staging,
// no vmcnt(0) serialization. LDS holds only the A tile + reduction scratch,
// so the 16-wave block gets 4 waves/SIMD.
// ---------------------------------------------------------------------------
// LDS layout (bytes):
//  [0,     32768)  A_hi : 64 rows x 256 d fp16; 16B-block s of row t at
//                         slot rotl3(s)^(t&31)
//  [32768, 65536)  A_lo : same layout
//  [65536, 69632)  bestS  float[16][64]
//  [69632, 73728)  bestI  int  [16][64]
//  [73728, 73984)  indF   int  [64]
//  [73984, 74048)  lossRed float[16]
#define LDS_BYTES 74048

__global__ __launch_bounds__(1024)
void vq_layer(const float* __restrict__ resIn, float* __restrict__ resOut,
              const float* __restrict__ embedTq, const float* __restrict__ e2q,
              const _Float16* __restrict__ embedBq, float* __restrict__ lossSumQ,
              int* __restrict__ countsQ) {
    extern __shared__ char smem[];
    _Float16* Ahi = (_Float16*)smem;
    _Float16* Alo = (_Float16*)(smem + 32768);
    float* bestS   = (float*)(smem + 65536);
    int*   bestI   = (int*)(smem + 69632);
    int*   indF    = (int*)(smem + 73728);
    float* lossRed = (float*)(smem + 73984);

    const int tid    = threadIdx.x;
    const int wave   = tid >> 6;       // 0..15
    const int lane   = tid & 63;
    const int l32    = lane & 31;
    const int h32    = lane >> 5;
    const int tok0   = blockIdx.x * TOKPB;
    const int codeBase = wave * 64;

    // ---- Phase 0: stage residual -> A hi/lo (swizzled) ----
#pragma unroll
    for (int k = 0; k < 2; ++k) {
        const int si = tid + k * 1024;         // 0..2047 (t,s) pairs
        const int t  = si >> 5;
        const int s  = si & 31;
        const float4 v0 = *(const float4*)(resIn + (tok0 + t) * 256 + s * 8);
        const float4 v1 = *(const float4*)(resIn + (tok0 + t) * 256 + s * 8 + 4);
        const float vv[8] = {v0.x, v0.y, v0.z, v0.w, v1.x, v1.y, v1.z, v1.w};
        f16x8 h8, l8;
#pragma unroll
        for (int e = 0; e < 8; ++e) {
            const _Float16 hi = (_Float16)vv[e];
            h8[e] = hi;
            l8[e] = (_Float16)(vv[e] - (float)hi);
        }
        const int ss = rotl3(s) ^ (t & 31);
        ((f16x8*)(Ahi + t * 256))[ss] = h8;
        ((f16x8*)(Alo + t * 256))[ss] = l8;
    }
    __syncthreads();

    // ---- K-loop: B register-resident, depth-1 prefetch ----
    f32x16 acc[2][2];
#pragma unroll
    for (int rt = 0; rt < 2; ++rt)
#pragma unroll
        for (int ct = 0; ct < 2; ++ct)
#pragma unroll
            for (int r = 0; r < 16; ++r) acc[rt][ct][r] = 0.f;

    // this lane's base into the (chunk, wave) 4 KB image
    const char* gBw = (const char*)embedBq + wave * 4096 + h32 * 1024 + l32 * 16;

    f16x8 bH[2][2], bL[2][2];
#pragma unroll
    for (int ct = 0; ct < 2; ++ct) {
        bH[0][ct] = *(const f16x8*)(gBw + ct * 512);
        bL[0][ct] = *(const f16x8*)(gBw + 2048 + ct * 512);
    }

#pragma unroll
    for (int c = 0; c < 16; ++c) {
        const int cur = c & 1, nxt = cur ^ 1;
        if (c < 15) {
            const char* gBn = gBw + (c + 1) * 65536;
#pragma unroll
            for (int ct = 0; ct < 2; ++ct) {
                bH[nxt][ct] = *(const f16x8*)(gBn + ct * 512);
                bL[nxt][ct] = *(const f16x8*)(gBn + 2048 + ct * 512);
            }
        }
        f16x8 aH[2], aL[2];
#pragma unroll
        for (int rt = 0; rt < 2; ++rt) {
            const int t  = rt * 32 + l32;
            const int ss = rotl3(2 * c + h32) ^ l32;
            aH[rt] = ((const f16x8*)(Ahi + t * 256))[ss];
            aL[rt] = ((const f16x8*)(Alo + t * 256))[ss];
        }
#pragma unroll
        for (int rt = 0; rt < 2; ++rt)
#pragma unroll
            for (int ct = 0; ct < 2; ++ct) {
                acc[rt][ct] = __builtin_amdgcn_mfma_f32_32x32x16_f16(
                    aH[rt], bH[cur][ct], acc[rt][ct], 0, 0, 0);
                acc[rt][ct] = __builtin_amdgcn_mfma_f32_32x32x16_f16(
                    aH[rt], bL[cur][ct], acc[rt][ct], 0, 0, 0);
                acc[rt][ct] = __builtin_amdgcn_mfma_f32_32x32x16_f16(
                    aL[rt], bH[cur][ct], acc[rt][ct], 0, 0, 0);
            }
    }

    // ---- scores + per-wave argmin ----
    float e2v[2];
#pragma unroll
    for (int ct = 0; ct < 2; ++ct)
        e2v[ct] = e2q[codeBase + ct * 32 + l32];

#pragma unroll
    for (int rt = 0; rt < 2; ++rt) {
#pragma unroll
        for (int r = 0; r < 16; ++r) {
            float bs = 3.4e38f;
            int   bi = 0x7fffffff;
#pragma unroll
            for (int ct = 0; ct < 2; ++ct) {
                const float sc = e2v[ct] - 2.0f * acc[rt][ct][r];
                const int   cd = codeBase + ct * 32 + l32;
                if (sc < bs || (sc == bs && cd < bi)) { bs = sc; bi = cd; }
            }
            // lexicographic min over the 32 lanes of this half
#pragma unroll
            for (int m = 1; m < 32; m <<= 1) {
                const float so = __shfl_xor(bs, m);
                const int   io = __shfl_xor(bi, m);
                if (so < bs || (so == bs && io < bi)) { bs = so; bi = io; }
            }
            if (l32 == 0) {
                const int row = rt * 32 + (r & 3) + 8 * (r >> 2) + 4 * h32;
                bestS[wave * 64 + row] = bs;
                bestI[wave * 64 + row] = bi;
            }
        }
    }
    __syncthreads();

    // ---- cross-wave argmin (waves cover ascending code ranges) ----
    if (tid < 64) {
        float bs = bestS[tid];
        int   bi = bestI[tid];
        for (int w = 1; w < 16; ++w) {
            const float s2 = bestS[w * 64 + tid];
            const int   i2 = bestI[w * 64 + tid];
            if (s2 < bs || (s2 == bs && i2 < bi)) { bs = s2; bi = i2; }
        }
        indF[tid] = bi;
        atomicAdd(&countsQ[bi], 1);
    }
    __syncthreads();

    // ---- update: r -= quantize (into LDS); loss partial ----
    {
        const int tl = tid >> 4;          // token 0..63
        const int sg = tid & 15;          // 16-dim strip
        const int csel = indF[tl];
        const float* gq = embedTq + csel * 256 + sg * 16;
        float lp = 0.f;
        f16x8* rowH = (f16x8*)(Ahi + tl * 256);
        f16x8* rowL = (f16x8*)(Alo + tl * 256);
#pragma unroll
        for (int it = 0; it < 2; ++it) {
            const int slot = rotl3(sg * 2 + it) ^ (tl & 31);
            f16x8 h8 = rowH[slot];
            f16x8 l8 = rowL[slot];
            const float4 q0 = *(const float4*)(gq + it * 8);
            const float4 q1 = *(const float4*)(gq + it * 8 + 4);
            const float qv[8] = {q0.x, q0.y, q0.z, q0.w, q1.x, q1.y, q1.z, q1.w};
#pragma unroll
            for (int e = 0; e < 8; ++e) {
                const float rv = (float)h8[e] + (float)l8[e];
                const float nr = rv - qv[e];
                lp += nr * nr;
                const _Float16 nh = (_Float16)nr;
                h8[e] = nh;
                l8[e] = (_Float16)(nr - (float)nh);
            }
            rowH[slot] = h8;
            rowL[slot] = l8;
        }
        // loss reduction: wave -> block -> global atomic
#pragma unroll
        for (int off = 32; off > 0; off >>= 1) lp += __shfl_down(lp, off);
        if (lane == 0) lossRed[wave] = lp;
    }
    __syncthreads();
    if (tid == 0) {
        float t = 0.f;
        for (int w = 0; w < 16; ++w) t += lossRed[w];
        atomicAdd(lossSumQ, t);
    }
    __syncthreads();

    // ---- writeback: new fp32 residual, coalesced ----
#pragma unroll
    for (int k = 0; k < 2; ++k) {
        const int si = tid + k * 1024;
        const int t  = si >> 5;
        const int s  = si & 31;
        const int ss = rotl3(s) ^ (t & 31);
        const f16x8 h8 = ((const f16x8*)(Ahi + t * 256))[ss];
        const f16x8 l8 = ((const f16x8*)(Alo + t * 256))[ss];
        float4 o0, o1;
        o0.x = (float)h8[0] + (float)l8[0];
        o0.y = (float)h8[1] + (float)l8[1];
        o0.z = (float)h8[2] + (float)l8[2];
        o0.w = (float)h8[3] + (float)l8[3];
        o1.x = (float)h8[4] + (float)l8[4];
        o1.y = (float)h8[5] + (float)l8[5];
        o1.z = (float)h8[6] + (float)l8[6];
        o1.w = (float)h8[7] + (float)l8[7];
        *(float4*)(resOut + (tok0 + t) * 256 + s * 8)     = o0;
        *(float4*)(resOut + (tok0 + t) * 256 + s * 8 + 4) = o1;
    }
}

// ---------------------------------------------------------------------------
// Epilogue: quantized_out = x - residual_final
// ---------------------------------------------------------------------------
__global__ __launch_bounds__(256)
void vq_out(const float* __restrict__ x, const float* __restrict__ residual,
            float* __restrict__ out) {
    const int i = blockIdx.x * 256 + threadIdx.x;     // float4 index
    const float4 xv = *(const float4*)(x + i * 4);
    const float4 rv = *(const float4*)(residual + i * 4);
    float4 o;
    o.x = xv.x - rv.x; o.y = xv.y - rv.y; o.z = xv.z - rv.z; o.w = xv.w - rv.w;
    *(float4*)(out + i * 4) = o;
}

// ---------------------------------------------------------------------------
// Finalize: losses + perplexities into the output tail.
// ---------------------------------------------------------------------------
__global__ __launch_bounds__(256)
void vq_finalize(const int* __restrict__ counts, const float* __restrict__ lossSum,
                 float* __restrict__ outTail) {
    const int q = blockIdx.x;
    const int tid = threadIdx.x;
    float s = 0.f;
    for (int k = tid; k < KCODES; k += 256) {
        const float p = (float)counts[q * KCODES + k] * (1.0f / 65536.0f);
        s += p * logf(p + 1e-10f);
    }
    for (int off = 32; off > 0; off >>= 1) s += __shfl_down(s, off);
    __shared__ float wpart[4];
    if ((tid & 63) == 0) wpart[tid >> 6] = s;
    __syncthreads();
    if (tid == 0) {
        outTail[q]     = lossSum[q] * (1.0f / 16777216.0f);   // mean * COMMITMENT
        outTail[8 + q] = expf(-(wpart[0] + wpart[1] + wpart[2] + wpart[3]));
    }
}

// ---------------------------------------------------------------------------
extern "C" void kernel_launch(void* const* d_in, const int* in_sizes, int n_in,
                              void* d_out, int out_size, void* d_ws, size_t ws_size,
                              hipStream_t stream) {
    const float* x      = (const float*)d_in[0];   // [32,2048,256]
    const float* embeds = (const float*)d_in[1];   // [8,256,1024]
    float* out = (float*)d_out;                    // 16777216 + 8 + 8

    // Workspace layout (float units unless noted):
    float* residual = (float*)d_ws;                     // 16,777,216
    float* embedT   = residual + NELEM;                 // 2,097,152
    float* e2       = embedT + 2097152;                 // 8,192
    float* lossSum  = e2 + 8192;                        // 8
    int*   counts   = (int*)(lossSum + 8);              // 8,192
    _Float16* embedB = (_Float16*)(counts + 8192);      // 4,194,304 halfs (8 MB)

    hipMemsetAsync(lossSum, 0, (8 + 8192) * sizeof(float), stream);

    vq_transpose<<<8192, 256, 0, stream>>>(embeds, embedT);
    vq_e2<<<32, 256, 0, stream>>>(embeds, e2);
    vq_embedB<<<16384, 256, 0, stream>>>(embeds, embedB);

    hipFuncSetAttribute((const void*)vq_layer,
                        hipFuncAttributeMaxDynamicSharedMemorySize, LDS_BYTES);
    for (int q = 0; q < NQ; ++q) {
        const float* resIn = (q == 0) ? x : residual;
        vq_layer<<<NTOK / TOKPB, 1024, LDS_BYTES, stream>>>(
            resIn, residual,
            embedT + q * (KCODES * DIMV), e2 + q * KCODES,
            embedB + q * 524288, lossSum + q, counts + q * KCODES);
    }

    vq_out<<<NELEM / 4 / 256, 256, 0, stream>>>(x, residual, out);
    vq_finalize<<<NQ, 256, 0, stream>>>(counts, lossSum, out + NELEM);
}